// Round 15
// baseline (377.479 us; speedup 1.0000x reference)
//
#include <hip/hip_runtime.h>
#include <math.h>

#define N_NODES 50000
#define MPAD    50048                              // 64*782 = 32*1564 = 16*3128
#define N_EDGES 800000
#define FDIM    128
#define NGRAPH  128

// deterministic multi-split CSR build
#define NCB   196                                  // coarse buckets (dst>>8, 256 nodes each)
#define CBN   256                                  // nodes per coarse bucket
#define ABLK  256                                  // histogram/scatter blocks
#define EPB   (N_EDGES / ABLK)                     // 3125 edges per block (exact)
#define CVT_BLOCKS ((MPAD * FDIM / 8 + 255) / 256) // 3128 convert blocks (8 floats/thread)
#define WCONV_BLOCKS 640                           // convert_w work folded into pre
#define STAGE_MAX 6656                             // LDS staging cap (bucket mean 4096, sd 64)

// R16 chunk-sorted edges, R17 fp8 rows, R25 16-node tiles, R26 scan2-fold: kept.
// R27: csr_src -> u16 (ids < 65536) + csr final pass LDS-staged, COALESCED writes
// (was 800K scattered 4B stores ~= 50MB write-allocate traffic). Sage = control.
// (R14 round was an infra failure — this is the same kernel resubmitted.)
#define NCHUNK 8
#define CHUNK_OF(s) ((int)(((u32)(s) * 671u) >> 22))   // monotone, ~6251 nodes/chunk, 0..7

typedef __attribute__((ext_vector_type(8))) short short8;   // 8 bf16 = 4 VGPRs
typedef __attribute__((ext_vector_type(4))) float f32x4;
typedef __attribute__((ext_vector_type(2))) float f32x2;
typedef unsigned int u32;

__device__ __forceinline__ unsigned short f2bf(float f) {   // RNE
    unsigned int u = __float_as_uint(f);
    return (unsigned short)((u + 0x7FFFu + ((u >> 16) & 1u)) >> 16);
}
__device__ __forceinline__ float bflo(unsigned int u) { return __uint_as_float(u << 16); }

// decode 16 fp8 (uint4) -> accumulate into acc[0..15]
#define ACC16(v) { \
    f32x2 d0 = __builtin_amdgcn_cvt_pk_f32_fp8((int)(v).x, false); \
    f32x2 d1 = __builtin_amdgcn_cvt_pk_f32_fp8((int)(v).x, true);  \
    f32x2 d2 = __builtin_amdgcn_cvt_pk_f32_fp8((int)(v).y, false); \
    f32x2 d3 = __builtin_amdgcn_cvt_pk_f32_fp8((int)(v).y, true);  \
    f32x2 d4 = __builtin_amdgcn_cvt_pk_f32_fp8((int)(v).z, false); \
    f32x2 d5 = __builtin_amdgcn_cvt_pk_f32_fp8((int)(v).z, true);  \
    f32x2 d6 = __builtin_amdgcn_cvt_pk_f32_fp8((int)(v).w, false); \
    f32x2 d7 = __builtin_amdgcn_cvt_pk_f32_fp8((int)(v).w, true);  \
    acc[0] += d0.x;  acc[1] += d0.y;  acc[2] += d1.x;  acc[3] += d1.y; \
    acc[4] += d2.x;  acc[5] += d2.y;  acc[6] += d3.x;  acc[7] += d3.y; \
    acc[8] += d4.x;  acc[9] += d4.y;  acc[10] += d5.x; acc[11] += d5.y; \
    acc[12] += d6.x; acc[13] += d6.y; acc[14] += d7.x; acc[15] += d7.y; }

struct WPtrs { const float* wl[5]; const float* wr[5]; };

// ------- pre: x convert | edge histogram | weight convert (fused, routed by blockIdx) -----
__global__ __launch_bounds__(256) void pre_kernel(const float* __restrict__ x,
                                                  unsigned short* __restrict__ xb,
                                                  unsigned char* __restrict__ xb8,
                                                  const int* __restrict__ edges,
                                                  int* __restrict__ g_hist,
                                                  WPtrs wp,
                                                  unsigned short* __restrict__ wcat,
                                                  const int* __restrict__ batch,
                                                  float* __restrict__ gsum,
                                                  float* __restrict__ invcnt) {
    __shared__ int hist[NCB];
    int t = threadIdx.x;
    if (blockIdx.x < CVT_BLOCKS) {
        int i = blockIdx.x * 256 + t;
        if (i >= MPAD * FDIM / 8) return;
        int base = i * 8;
        uint4 o; uint2 o8;
        if (base < N_NODES * FDIM) {
            float4 v0 = *(const float4*)&x[base];
            float4 v1 = *(const float4*)&x[base + 4];
            o.x = (u32)f2bf(v0.x) | ((u32)f2bf(v0.y) << 16);
            o.y = (u32)f2bf(v0.z) | ((u32)f2bf(v0.w) << 16);
            o.z = (u32)f2bf(v1.x) | ((u32)f2bf(v1.y) << 16);
            o.w = (u32)f2bf(v1.z) | ((u32)f2bf(v1.w) << 16);
            int p8a = __builtin_amdgcn_cvt_pk_fp8_f32(v0.x, v0.y, 0, false);
            p8a = __builtin_amdgcn_cvt_pk_fp8_f32(v0.z, v0.w, p8a, true);
            int p8b = __builtin_amdgcn_cvt_pk_fp8_f32(v1.x, v1.y, 0, false);
            p8b = __builtin_amdgcn_cvt_pk_fp8_f32(v1.z, v1.w, p8b, true);
            o8.x = (u32)p8a; o8.y = (u32)p8b;
        } else { o.x = o.y = o.z = o.w = 0u; o8.x = o8.y = 0u; }
        *(uint4*)&xb[base] = o;
        *(uint2*)&xb8[base] = o8;
    } else if (blockIdx.x < CVT_BLOCKS + ABLK) {
        int blk = blockIdx.x - CVT_BLOCKS;
        if (t < NCB) hist[t] = 0;
        __syncthreads();
        int beg = blk * EPB, end = beg + EPB;
        for (int i = beg + t; i < end; i += 256) {
            int2 ed = ((const int2*)edges)[i];
            atomicAdd(&hist[ed.y >> 8], 1);
        }
        __syncthreads();
        if (t < NCB) g_hist[t * ABLK + blk] = hist[t];
    } else {
        int tg = (blockIdx.x - CVT_BLOCKS - ABLK) * 256 + t;   // 0 .. 163839
        if (tg < NGRAPH * FDIM) gsum[tg] = 0.0f;
        if (tg < NGRAPH) {
            int g = tg;
            int lo = 0, hi = N_NODES;
            while (lo < hi) { int mid = (lo + hi) >> 1; if (batch[mid] < g) lo = mid + 1; else hi = mid; }
            int beg = lo;
            hi = N_NODES;
            while (lo < hi) { int mid = (lo + hi) >> 1; if (batch[mid] < g + 1) lo = mid + 1; else hi = mid; }
            invcnt[g] = 1.0f / (float)max(lo - beg, 1);
        }
        int l = tg >> 15;
        int rem = tg & 32767;
        int k = rem >> 7;        // 0..255
        int n = rem & 127;       // coalesced read over n
        const float* W = (k < 128) ? wp.wl[l] : wp.wr[l];
        float v = W[(k & 127) * 128 + n];
        wcat[((size_t)l << 15) + n * 256 + k] = f2bf(v);
    }
}

// ---------------- scan1: per-bucket wave-parallel exclusive scan over 256 blocks ----------
__global__ __launch_bounds__(64) void scan1_kernel(const int* __restrict__ g_hist,
                                                   int* __restrict__ g_base,
                                                   int* __restrict__ cbtotal,
                                                   int* __restrict__ row_ptr) {
    int cbi = blockIdx.x, l = threadIdx.x;          // 196 blocks x 1 wave
    if (cbi == 0 && l == 0) row_ptr[N_NODES] = N_EDGES;
    int4 v = ((const int4*)(g_hist + cbi * ABLK))[l];
    int s1 = v.x + v.y, s2 = s1 + v.z, s3 = s2 + v.w;   // lane-local inclusive
    int inc = s3;
    #pragma unroll
    for (int off = 1; off < 64; off <<= 1) {
        int nv = __shfl_up(inc, off, 64);
        if (l >= off) inc += nv;
    }
    int excl = inc - s3;
    int4 o; o.x = excl; o.y = excl + v.x; o.z = excl + s1; o.w = excl + s2;
    ((int4*)(g_base + cbi * ABLK))[l] = o;
    if (l == 63) cbtotal[cbi] = inc;
}

// helper: wave 0 computes exclusive scan of cbtotal[0..195] into cbb[] (LDS)
__device__ __forceinline__ void scan_cbtotal(const int* __restrict__ cbtotal,
                                             int* cbb, int t) {
    if (t < 64) {
        int i0 = t * 4;
        int a0 = (i0 + 0 < NCB) ? cbtotal[i0 + 0] : 0;
        int a1 = (i0 + 1 < NCB) ? cbtotal[i0 + 1] : 0;
        int a2 = (i0 + 2 < NCB) ? cbtotal[i0 + 2] : 0;
        int a3 = (i0 + 3 < NCB) ? cbtotal[i0 + 3] : 0;
        int s1 = a0 + a1, s2 = s1 + a2, s3 = s2 + a3;
        int inc = s3;
        #pragma unroll
        for (int off = 1; off < 64; off <<= 1) {
            int nv = __shfl_up(inc, off, 64);
            if (t >= off) inc += nv;
        }
        int excl = inc - s3;
        if (i0 + 0 < NCB) cbb[i0 + 0] = excl;
        if (i0 + 1 < NCB) cbb[i0 + 1] = excl + a0;
        if (i0 + 2 < NCB) cbb[i0 + 2] = excl + s1;
        if (i0 + 3 < NCB) cbb[i0 + 3] = excl + s2;
    }
}

// ---------------- A2: deterministic scatter into coarse buckets ----------------
__global__ __launch_bounds__(256) void scatter_kernel(const int* __restrict__ edges,
                                                      const int* __restrict__ g_base,
                                                      const int* __restrict__ cbtotal,
                                                      u32* __restrict__ coarse) {
    __shared__ int cur[NCB];
    __shared__ int cbb[NCB];
    int t = threadIdx.x, blk = blockIdx.x;
    scan_cbtotal(cbtotal, cbb, t);           // local 196-scan (replaces scan2)
    __syncthreads();
    if (t < NCB) cur[t] = g_base[t * ABLK + blk] + cbb[t];
    __syncthreads();
    int beg = blk * EPB, end = beg + EPB;
    for (int i = beg + t; i < end; i += 256) {
        int2 ed = ((const int2*)edges)[i];   // x=src, y=dst
        int cb = ed.y >> 8;
        int pos = atomicAdd(&cur[cb], 1);
        coarse[pos] = ((u32)(ed.y & 255) << 16) | (u32)ed.x;
    }
}

// ---------------- B: per-coarse-bucket LDS counting sort by (dst, src-chunk) ----------
// R27: sort into LDS stage, then write csr_src (u16) COALESCED.
__global__ __launch_bounds__(256) void csr_kernel(const int* __restrict__ cbtotal,
                                                  const u32* __restrict__ coarse,
                                                  unsigned short* __restrict__ csr_src,
                                                  int* __restrict__ row_ptr,
                                                  float* __restrict__ invdeg) {
    __shared__ int cnt[CBN][NCHUNK];   // 8 KB: per-(dst,chunk) cell counts -> cursors
    __shared__ int dbase[CBN];         // per-dst totals -> bucket-RELATIVE dst starts
    __shared__ int cbb[NCB];
    __shared__ unsigned short stage[STAGE_MAX];   // 13 KB sorted staging
    int cb = blockIdx.x, t = threadIdx.x;
    scan_cbtotal(cbtotal, cbb, t);           // local 196-scan (replaces scan2)
    #pragma unroll
    for (int c0 = 0; c0 < NCHUNK; ++c0) cnt[t][c0] = 0;
    __syncthreads();
    int n = cbtotal[cb], base = cbb[cb];
    const u32* ce = coarse + base;
    for (int i = t; i < n; i += 256) {
        u32 ev = ce[i];
        atomicAdd(&cnt[ev >> 16][CHUNK_OF(ev & 0xFFFFu)], 1);
    }
    __syncthreads();
    {   // per-dst exclusive scan over its 8 chunk cells (thread t owns dst t)
        int run = 0;
        #pragma unroll
        for (int c0 = 0; c0 < NCHUNK; ++c0) { int v = cnt[t][c0]; cnt[t][c0] = run; run += v; }
        dbase[t] = run;
    }
    __syncthreads();
    if (t < 64) {   // wave-parallel exclusive scan of 256 dst totals (bucket-relative)
        int i0 = t * 4;
        int a0 = dbase[i0 + 0], a1 = dbase[i0 + 1], a2 = dbase[i0 + 2], a3 = dbase[i0 + 3];
        int s1 = a0 + a1, s2 = s1 + a2, s3 = s2 + a3;
        int inc = s3;
        #pragma unroll
        for (int off = 1; off < 64; off <<= 1) {
            int nv = __shfl_up(inc, off, 64);
            if (t >= off) inc += nv;
        }
        int excl = inc - s3;                 // RELATIVE (no base)
        dbase[i0 + 0] = excl;
        dbase[i0 + 1] = excl + a0;
        dbase[i0 + 2] = excl + s1;
        dbase[i0 + 3] = excl + s2;
    }
    __syncthreads();
    {   // relative cell starts; emit row_ptr + invdeg before cursors move
        int db = dbase[t];
        int deg = ((t == CBN - 1) ? n : dbase[t + 1]) - db;
        #pragma unroll
        for (int c0 = 0; c0 < NCHUNK; ++c0) cnt[t][c0] += db;
        int node = cb * CBN + t;
        if (node < N_NODES) {
            row_ptr[node] = base + db;
            invdeg[node] = 1.0f / (float)max(deg, 1);
        }
    }
    __syncthreads();
    for (int i = t; i < n; i += 256) {       // sort into LDS (relative positions)
        u32 ev = ce[i];
        int pos = atomicAdd(&cnt[ev >> 16][CHUNK_OF(ev & 0xFFFFu)], 1);
        stage[pos] = (unsigned short)(ev & 0xFFFFu);
    }
    __syncthreads();
    for (int i = t; i < n; i += 256)         // coalesced u16 writes
        csr_src[base + i] = stage[i];
}

// ---------------- fused SAGE layer: fp8 gather agg tile into LDS, then MFMA ----------------
// R25 form (proven 47.3 us); R27: csr_src read as u16 (scalar loads, any alignment).
__global__ __launch_bounds__(128) void sage_fused_kernel(
        const unsigned short* __restrict__ h,    // [MPAD][128] bf16 (self term)
        const unsigned char*  __restrict__ h8,   // [MPAD][128] fp8  (gather)
        const int* __restrict__ row_ptr,
        const unsigned short* __restrict__ csr_src,
        const float* __restrict__ invdeg,
        const unsigned short* __restrict__ Wcat, // [128 n][256 k] bf16
        const float* __restrict__ bias,
        unsigned short* __restrict__ out,
        unsigned char*  __restrict__ out8,       // fp8 copy for next layer's gather (null l=4)
        const int* __restrict__ pool_batch,      // null for layers 1-4
        float* __restrict__ gsum) {
    __shared__ unsigned short As[16][136];
    int t = threadIdx.x;
    int node0 = blockIdx.x * 16;

    // ---- phase 1: gather (16 node-slots x 8 lanes, one pass) ----
    {
        int slot = t >> 3;       // 0..15
        int lane = t & 7;
        int c = lane * 16;       // feature offset (16 fp8 per lane)
        int node = node0 + slot;
        float acc[16];
        #pragma unroll
        for (int i = 0; i < 16; ++i) acc[i] = 0.f;
        if (node < N_NODES) {
            int beg = row_ptr[node], end = row_ptr[node + 1];
            int e = beg;
            for (; e + 4 <= end; e += 4) {
                int s0 = csr_src[e + 0];
                int s1 = csr_src[e + 1];
                int s2 = csr_src[e + 2];
                int s3 = csr_src[e + 3];
                uint4 v0 = *(const uint4*)&h8[(size_t)s0 * FDIM + c];
                uint4 v1 = *(const uint4*)&h8[(size_t)s1 * FDIM + c];
                uint4 v2 = *(const uint4*)&h8[(size_t)s2 * FDIM + c];
                uint4 v3 = *(const uint4*)&h8[(size_t)s3 * FDIM + c];
                ACC16(v0); ACC16(v1); ACC16(v2); ACC16(v3);
            }
            for (; e < end; ++e) {
                int s = csr_src[e];
                uint4 v = *(const uint4*)&h8[(size_t)s * FDIM + c];
                ACC16(v);
            }
            float inv = invdeg[node];
            #pragma unroll
            for (int i = 0; i < 16; ++i) acc[i] *= inv;
        }
        uint4 o0, o1;
        o0.x = (u32)f2bf(acc[0])  | ((u32)f2bf(acc[1])  << 16);
        o0.y = (u32)f2bf(acc[2])  | ((u32)f2bf(acc[3])  << 16);
        o0.z = (u32)f2bf(acc[4])  | ((u32)f2bf(acc[5])  << 16);
        o0.w = (u32)f2bf(acc[6])  | ((u32)f2bf(acc[7])  << 16);
        o1.x = (u32)f2bf(acc[8])  | ((u32)f2bf(acc[9])  << 16);
        o1.y = (u32)f2bf(acc[10]) | ((u32)f2bf(acc[11]) << 16);
        o1.z = (u32)f2bf(acc[12]) | ((u32)f2bf(acc[13]) << 16);
        o1.w = (u32)f2bf(acc[14]) | ((u32)f2bf(acc[15]) << 16);
        *(uint4*)&As[slot][c] = o0;
        *(uint4*)&As[slot][c + 8] = o1;
    }
    __syncthreads();

    // ---- phase 2: MFMA (2 waves; wave = col-half; 16 rows x 64 cols each) ----
    int wave = t >> 6;                   // 0..1
    int lane = t & 63;
    int l15 = lane & 15;
    int q = lane >> 4;
    int half = wave;                     // col-blocks half*4 .. half*4+3

    f32x4 acc[4];
    #pragma unroll
    for (int i = 0; i < 4; ++i) acc[i] = (f32x4){0.f, 0.f, 0.f, 0.f};

    // p=0: A = agg tile (LDS), Wl (k<128)
    {
        const unsigned short* Wb = Wcat + (size_t)(half * 64 + l15) * 256 + q * 8;
        #pragma unroll
        for (int k0 = 0; k0 < 128; k0 += 32) {
            short8 a = *(const short8*)&As[l15][q * 8 + k0];
            #pragma unroll
            for (int j = 0; j < 4; ++j) {
                short8 b = *(const short8*)(Wb + (size_t)j * 16 * 256 + k0);
                acc[j] = __builtin_amdgcn_mfma_f32_16x16x32_bf16(a, b, acc[j], 0, 0, 0);
            }
        }
    }
    // p=1: A = h (global bf16), Wr (k>=128)
    {
        const unsigned short* Ab = h + (size_t)(node0 + l15) * FDIM + q * 8;
        const unsigned short* Wb = Wcat + (size_t)(half * 64 + l15) * 256 + 128 + q * 8;
        #pragma unroll
        for (int k0 = 0; k0 < 128; k0 += 32) {
            short8 a = *(const short8*)(Ab + k0);
            #pragma unroll
            for (int j = 0; j < 4; ++j) {
                short8 b = *(const short8*)(Wb + (size_t)j * 16 * 256 + k0);
                acc[j] = __builtin_amdgcn_mfma_f32_16x16x32_bf16(a, b, acc[j], 0, 0, 0);
            }
        }
    }

    if (pool_batch == nullptr) {
        // epilogue: bias + relu + bf16 store + fp8 store (next layer's gather copy)
        #pragma unroll
        for (int j = 0; j < 4; ++j) {
            int col = (half * 4 + j) * 16 + l15;
            float bv = bias[col];
            #pragma unroll
            for (int r = 0; r < 4; ++r) {
                int row = node0 + q * 4 + r;
                float v = fmaxf(acc[j][r] + bv, 0.f);
                out[(size_t)row * FDIM + col] = f2bf(v);
                int pk = __builtin_amdgcn_cvt_pk_fp8_f32(v, v, 0, false);
                out8[(size_t)row * FDIM + col] = (unsigned char)(pk & 0xff);
            }
        }
    } else {
        // layer-5 epilogue: stage relu tile in LDS, in-block sorted-batch reduction
        __syncthreads();                 // all waves done READING As (p=0)
        #pragma unroll
        for (int j = 0; j < 4; ++j) {
            int col = (half * 4 + j) * 16 + l15;
            float bv = bias[col];
            #pragma unroll
            for (int r = 0; r < 4; ++r) {
                int rl = q * 4 + r;
                As[rl][col] = f2bf(fmaxf(acc[j][r] + bv, 0.f));
            }
        }
        __syncthreads();
        {   // t in [0,128): one thread per feature column
            int f = t;
            int nmax = min(16, N_NODES - node0);
            float a = 0.0f;
            int cur = pool_batch[node0];
            for (int r = 0; r < nmax; ++r) {
                int b = pool_batch[node0 + r];     // broadcast read
                if (b != cur) {
                    atomicAdd(&gsum[cur * FDIM + f], a);
                    a = 0.0f;
                    cur = b;
                }
                a += bflo((u32)As[r][f]);
            }
            atomicAdd(&gsum[cur * FDIM + f], a);
        }
    }
}

// ---------------- final MLP head (fp32): sigmoid(relu((gsum/cnt)@Wf1+bf1)@Wf2+bf2) -------
__global__ void mlp_kernel(const float* __restrict__ gsum,
                           const float* __restrict__ invcnt,
                           const float* __restrict__ Wf1, const float* __restrict__ bf1,
                           const float* __restrict__ Wf2, const float* __restrict__ bf2,
                           float* __restrict__ out) {
    int gg = blockIdx.x;
    int j = threadIdx.x;   // 128
    __shared__ float row[128];
    __shared__ float red[128];
    row[j] = gsum[gg * 128 + j] * invcnt[gg];
    __syncthreads();
    float acc = bf1[j];
    for (int k = 0; k < 128; ++k) acc = fmaf(row[k], Wf1[k * 128 + j], acc);
    float v = fmaxf(acc, 0.0f);
    red[j] = v * Wf2[j];
    __syncthreads();
    for (int off = 64; off > 0; off >>= 1) {
        if (j < off) red[j] += red[j + off];
        __syncthreads();
    }
    if (j == 0) out[gg] = 1.0f / (1.0f + expf(-(red[0] + bf2[0])));
}

extern "C" void kernel_launch(void* const* d_in, const int* in_sizes, int n_in,
                              void* d_out, int out_size, void* d_ws, size_t ws_size,
                              hipStream_t stream) {
    const float* x      = (const float*)d_in[0];
    const int*   edges  = (const int*)d_in[1];
    const int*   batch  = (const int*)d_in[2];
    WPtrs wp;
    const float* bs[5];
    for (int l = 0; l < 5; ++l) {
        wp.wl[l] = (const float*)d_in[3 + 3 * l];
        wp.wr[l] = (const float*)d_in[4 + 3 * l];
        bs[l]    = (const float*)d_in[5 + 3 * l];
    }
    const float* Wf1 = (const float*)d_in[18];
    const float* bf1 = (const float*)d_in[19];
    const float* Wf2 = (const float*)d_in[20];
    const float* bf2 = (const float*)d_in[21];
    float* out = (float*)d_out;

    // workspace carve-up (256B aligned)
    char* ws = (char*)d_ws;
    auto alloc = [&](size_t bytes) { void* p = (void*)ws; ws += (bytes + 255) & ~(size_t)255; return p; };
    unsigned short* xb   = (unsigned short*)alloc((size_t)MPAD * FDIM * 2);
    unsigned short* hA   = (unsigned short*)alloc((size_t)MPAD * FDIM * 2);
    unsigned short* hB   = (unsigned short*)alloc((size_t)MPAD * FDIM * 2);
    unsigned short* wcat = (unsigned short*)alloc((size_t)5 * 128 * 256 * 2);
    u32*   coarse   = (u32*)alloc((size_t)N_EDGES * 4);
    int*   g_hist   = (int*)alloc((size_t)NCB * ABLK * 4);
    int*   g_base   = (int*)alloc((size_t)NCB * ABLK * 4);
    int*   cbtotal  = (int*)alloc((size_t)NCB * 4);
    int*   row_ptr  = (int*)alloc((size_t)(N_NODES + 1) * 4);
    unsigned short* csr_src = (unsigned short*)alloc((size_t)N_EDGES * 2);   // R27: u16
    float* invdeg   = (float*)alloc((size_t)N_NODES * 4);
    float* gsum     = (float*)alloc((size_t)NGRAPH * FDIM * 4);
    float* invcnt   = (float*)alloc((size_t)NGRAPH * 4);
    unsigned char* h8A = (unsigned char*)alloc((size_t)MPAD * FDIM);  // +6.4 MB
    // lifetime-aliased fp8 buffers (no extra ws):
    //   xb8 lives in hB  : read by layer 0 only; hB first written by layer 1.
    //   h8B lives in xb  : xb dead after layer 0; h8B written by layer 1.
    unsigned char* xb8 = (unsigned char*)hB;
    unsigned char* h8B = (unsigned char*)xb;
    (void)ws_size; (void)in_sizes; (void)n_in; (void)out_size;

    // ---- conversions + CSR build (deterministic multi-split, (dst,src-chunk) order) ----
    pre_kernel<<<CVT_BLOCKS + ABLK + WCONV_BLOCKS, 256, 0, stream>>>(
        x, xb, xb8, edges, g_hist, wp, wcat, batch, gsum, invcnt);
    scan1_kernel<<<NCB, 64, 0, stream>>>(g_hist, g_base, cbtotal, row_ptr);
    scatter_kernel<<<ABLK, 256, 0, stream>>>(edges, g_base, cbtotal, coarse);
    csr_kernel<<<NCB, 256, 0, stream>>>(cbtotal, coarse, csr_src, row_ptr, invdeg);

    // ---- 5 fused SAGE layers; layer 5 folds the graph mean-pool ----
    const unsigned short* hcur  = xb;
    const unsigned char*  h8cur = xb8;
    unsigned short* bufs[2]  = {hA, hB};
    unsigned char*  bufs8[2] = {h8A, h8B};
    for (int l = 0; l < 5; ++l) {
        unsigned short* hnext  = bufs[l & 1];
        unsigned char*  h8next = (l == 4) ? nullptr : bufs8[l & 1];
        const int* pb = (l == 4) ? batch : nullptr;
        sage_fused_kernel<<<MPAD / 16, 128, 0, stream>>>(
            hcur, h8cur, row_ptr, csr_src, invdeg, wcat + ((size_t)l << 15), bs[l],
            hnext, h8next, pb, gsum);
        hcur = hnext;
        h8cur = bufs8[l & 1];
    }

    // ---- head ----
    mlp_kernel<<<NGRAPH, 128, 0, stream>>>(gsum, invcnt, Wf1, bf1, Wf2, bf2, out);
}

// Round 16
// 366.957 us; speedup vs baseline: 1.0287x; 1.0287x over previous
//
#include <hip/hip_runtime.h>
#include <math.h>

#define N_NODES 50000
#define MPAD    50048                              // 64*782 = 32*1564 = 16*3128
#define N_EDGES 800000
#define FDIM    128
#define NGRAPH  128

// deterministic multi-split CSR build
#define NCB   196                                  // coarse buckets (dst>>8, 256 nodes each)
#define CBN   256                                  // nodes per coarse bucket
#define ABLK  256                                  // histogram/scatter blocks
#define EPB   (N_EDGES / ABLK)                     // 3125 edges per block (exact)
#define CVT_BLOCKS ((MPAD * FDIM / 8 + 255) / 256) // 3128 convert blocks (8 floats/thread)
#define WCONV_BLOCKS 640                           // convert_w work folded into pre
#define STAGE_MAX 6656                             // LDS staging cap (bucket mean 4096, sd 64)

// R16 chunk-sorted edges, R17 fp8 rows, R25 16-node tiles, R26 scan2-fold: kept.
// R27 postmortem: csr LDS-staged coalesced write WON (~6us); u16 csr_src REGRESSED
// sage (+3us/layer: killed the dwordx4 index-load merge on the critical issue path).
// R28: csr_src back to int32 (sage = R25 byte-identical, 47.3us) + keep the
// LDS-staged coalesced csr write (stage as u32, 26KB LDS).
#define NCHUNK 8
#define CHUNK_OF(s) ((int)(((u32)(s) * 671u) >> 22))   // monotone, ~6251 nodes/chunk, 0..7

typedef __attribute__((ext_vector_type(8))) short short8;   // 8 bf16 = 4 VGPRs
typedef __attribute__((ext_vector_type(4))) float f32x4;
typedef __attribute__((ext_vector_type(2))) float f32x2;
typedef unsigned int u32;

__device__ __forceinline__ unsigned short f2bf(float f) {   // RNE
    unsigned int u = __float_as_uint(f);
    return (unsigned short)((u + 0x7FFFu + ((u >> 16) & 1u)) >> 16);
}
__device__ __forceinline__ float bflo(unsigned int u) { return __uint_as_float(u << 16); }

// decode 16 fp8 (uint4) -> accumulate into acc[0..15]
#define ACC16(v) { \
    f32x2 d0 = __builtin_amdgcn_cvt_pk_f32_fp8((int)(v).x, false); \
    f32x2 d1 = __builtin_amdgcn_cvt_pk_f32_fp8((int)(v).x, true);  \
    f32x2 d2 = __builtin_amdgcn_cvt_pk_f32_fp8((int)(v).y, false); \
    f32x2 d3 = __builtin_amdgcn_cvt_pk_f32_fp8((int)(v).y, true);  \
    f32x2 d4 = __builtin_amdgcn_cvt_pk_f32_fp8((int)(v).z, false); \
    f32x2 d5 = __builtin_amdgcn_cvt_pk_f32_fp8((int)(v).z, true);  \
    f32x2 d6 = __builtin_amdgcn_cvt_pk_f32_fp8((int)(v).w, false); \
    f32x2 d7 = __builtin_amdgcn_cvt_pk_f32_fp8((int)(v).w, true);  \
    acc[0] += d0.x;  acc[1] += d0.y;  acc[2] += d1.x;  acc[3] += d1.y; \
    acc[4] += d2.x;  acc[5] += d2.y;  acc[6] += d3.x;  acc[7] += d3.y; \
    acc[8] += d4.x;  acc[9] += d4.y;  acc[10] += d5.x; acc[11] += d5.y; \
    acc[12] += d6.x; acc[13] += d6.y; acc[14] += d7.x; acc[15] += d7.y; }

struct WPtrs { const float* wl[5]; const float* wr[5]; };

// ------- pre: x convert | edge histogram | weight convert (fused, routed by blockIdx) -----
__global__ __launch_bounds__(256) void pre_kernel(const float* __restrict__ x,
                                                  unsigned short* __restrict__ xb,
                                                  unsigned char* __restrict__ xb8,
                                                  const int* __restrict__ edges,
                                                  int* __restrict__ g_hist,
                                                  WPtrs wp,
                                                  unsigned short* __restrict__ wcat,
                                                  const int* __restrict__ batch,
                                                  float* __restrict__ gsum,
                                                  float* __restrict__ invcnt) {
    __shared__ int hist[NCB];
    int t = threadIdx.x;
    if (blockIdx.x < CVT_BLOCKS) {
        int i = blockIdx.x * 256 + t;
        if (i >= MPAD * FDIM / 8) return;
        int base = i * 8;
        uint4 o; uint2 o8;
        if (base < N_NODES * FDIM) {
            float4 v0 = *(const float4*)&x[base];
            float4 v1 = *(const float4*)&x[base + 4];
            o.x = (u32)f2bf(v0.x) | ((u32)f2bf(v0.y) << 16);
            o.y = (u32)f2bf(v0.z) | ((u32)f2bf(v0.w) << 16);
            o.z = (u32)f2bf(v1.x) | ((u32)f2bf(v1.y) << 16);
            o.w = (u32)f2bf(v1.z) | ((u32)f2bf(v1.w) << 16);
            int p8a = __builtin_amdgcn_cvt_pk_fp8_f32(v0.x, v0.y, 0, false);
            p8a = __builtin_amdgcn_cvt_pk_fp8_f32(v0.z, v0.w, p8a, true);
            int p8b = __builtin_amdgcn_cvt_pk_fp8_f32(v1.x, v1.y, 0, false);
            p8b = __builtin_amdgcn_cvt_pk_fp8_f32(v1.z, v1.w, p8b, true);
            o8.x = (u32)p8a; o8.y = (u32)p8b;
        } else { o.x = o.y = o.z = o.w = 0u; o8.x = o8.y = 0u; }
        *(uint4*)&xb[base] = o;
        *(uint2*)&xb8[base] = o8;
    } else if (blockIdx.x < CVT_BLOCKS + ABLK) {
        int blk = blockIdx.x - CVT_BLOCKS;
        if (t < NCB) hist[t] = 0;
        __syncthreads();
        int beg = blk * EPB, end = beg + EPB;
        for (int i = beg + t; i < end; i += 256) {
            int2 ed = ((const int2*)edges)[i];
            atomicAdd(&hist[ed.y >> 8], 1);
        }
        __syncthreads();
        if (t < NCB) g_hist[t * ABLK + blk] = hist[t];
    } else {
        int tg = (blockIdx.x - CVT_BLOCKS - ABLK) * 256 + t;   // 0 .. 163839
        if (tg < NGRAPH * FDIM) gsum[tg] = 0.0f;
        if (tg < NGRAPH) {
            int g = tg;
            int lo = 0, hi = N_NODES;
            while (lo < hi) { int mid = (lo + hi) >> 1; if (batch[mid] < g) lo = mid + 1; else hi = mid; }
            int beg = lo;
            hi = N_NODES;
            while (lo < hi) { int mid = (lo + hi) >> 1; if (batch[mid] < g + 1) lo = mid + 1; else hi = mid; }
            invcnt[g] = 1.0f / (float)max(lo - beg, 1);
        }
        int l = tg >> 15;
        int rem = tg & 32767;
        int k = rem >> 7;        // 0..255
        int n = rem & 127;       // coalesced read over n
        const float* W = (k < 128) ? wp.wl[l] : wp.wr[l];
        float v = W[(k & 127) * 128 + n];
        wcat[((size_t)l << 15) + n * 256 + k] = f2bf(v);
    }
}

// ---------------- scan1: per-bucket wave-parallel exclusive scan over 256 blocks ----------
__global__ __launch_bounds__(64) void scan1_kernel(const int* __restrict__ g_hist,
                                                   int* __restrict__ g_base,
                                                   int* __restrict__ cbtotal,
                                                   int* __restrict__ row_ptr) {
    int cbi = blockIdx.x, l = threadIdx.x;          // 196 blocks x 1 wave
    if (cbi == 0 && l == 0) row_ptr[N_NODES] = N_EDGES;
    int4 v = ((const int4*)(g_hist + cbi * ABLK))[l];
    int s1 = v.x + v.y, s2 = s1 + v.z, s3 = s2 + v.w;   // lane-local inclusive
    int inc = s3;
    #pragma unroll
    for (int off = 1; off < 64; off <<= 1) {
        int nv = __shfl_up(inc, off, 64);
        if (l >= off) inc += nv;
    }
    int excl = inc - s3;
    int4 o; o.x = excl; o.y = excl + v.x; o.z = excl + s1; o.w = excl + s2;
    ((int4*)(g_base + cbi * ABLK))[l] = o;
    if (l == 63) cbtotal[cbi] = inc;
}

// helper: wave 0 computes exclusive scan of cbtotal[0..195] into cbb[] (LDS)
__device__ __forceinline__ void scan_cbtotal(const int* __restrict__ cbtotal,
                                             int* cbb, int t) {
    if (t < 64) {
        int i0 = t * 4;
        int a0 = (i0 + 0 < NCB) ? cbtotal[i0 + 0] : 0;
        int a1 = (i0 + 1 < NCB) ? cbtotal[i0 + 1] : 0;
        int a2 = (i0 + 2 < NCB) ? cbtotal[i0 + 2] : 0;
        int a3 = (i0 + 3 < NCB) ? cbtotal[i0 + 3] : 0;
        int s1 = a0 + a1, s2 = s1 + a2, s3 = s2 + a3;
        int inc = s3;
        #pragma unroll
        for (int off = 1; off < 64; off <<= 1) {
            int nv = __shfl_up(inc, off, 64);
            if (t >= off) inc += nv;
        }
        int excl = inc - s3;
        if (i0 + 0 < NCB) cbb[i0 + 0] = excl;
        if (i0 + 1 < NCB) cbb[i0 + 1] = excl + a0;
        if (i0 + 2 < NCB) cbb[i0 + 2] = excl + s1;
        if (i0 + 3 < NCB) cbb[i0 + 3] = excl + s2;
    }
}

// ---------------- A2: deterministic scatter into coarse buckets ----------------
__global__ __launch_bounds__(256) void scatter_kernel(const int* __restrict__ edges,
                                                      const int* __restrict__ g_base,
                                                      const int* __restrict__ cbtotal,
                                                      u32* __restrict__ coarse) {
    __shared__ int cur[NCB];
    __shared__ int cbb[NCB];
    int t = threadIdx.x, blk = blockIdx.x;
    scan_cbtotal(cbtotal, cbb, t);           // local 196-scan (replaces scan2)
    __syncthreads();
    if (t < NCB) cur[t] = g_base[t * ABLK + blk] + cbb[t];
    __syncthreads();
    int beg = blk * EPB, end = beg + EPB;
    for (int i = beg + t; i < end; i += 256) {
        int2 ed = ((const int2*)edges)[i];   // x=src, y=dst
        int cb = ed.y >> 8;
        int pos = atomicAdd(&cur[cb], 1);
        coarse[pos] = ((u32)(ed.y & 255) << 16) | (u32)ed.x;
    }
}

// ---------------- B: per-coarse-bucket LDS counting sort by (dst, src-chunk) ----------
// R27/R28: sort into LDS stage (u32), then write csr_src (int) COALESCED.
__global__ __launch_bounds__(256) void csr_kernel(const int* __restrict__ cbtotal,
                                                  const u32* __restrict__ coarse,
                                                  int* __restrict__ csr_src,
                                                  int* __restrict__ row_ptr,
                                                  float* __restrict__ invdeg) {
    __shared__ int cnt[CBN][NCHUNK];   // 8 KB: per-(dst,chunk) cell counts -> cursors
    __shared__ int dbase[CBN];         // per-dst totals -> bucket-RELATIVE dst starts
    __shared__ int cbb[NCB];
    __shared__ int stage[STAGE_MAX];   // 26 KB sorted staging (int)
    int cb = blockIdx.x, t = threadIdx.x;
    scan_cbtotal(cbtotal, cbb, t);           // local 196-scan (replaces scan2)
    #pragma unroll
    for (int c0 = 0; c0 < NCHUNK; ++c0) cnt[t][c0] = 0;
    __syncthreads();
    int n = cbtotal[cb], base = cbb[cb];
    const u32* ce = coarse + base;
    for (int i = t; i < n; i += 256) {
        u32 ev = ce[i];
        atomicAdd(&cnt[ev >> 16][CHUNK_OF(ev & 0xFFFFu)], 1);
    }
    __syncthreads();
    {   // per-dst exclusive scan over its 8 chunk cells (thread t owns dst t)
        int run = 0;
        #pragma unroll
        for (int c0 = 0; c0 < NCHUNK; ++c0) { int v = cnt[t][c0]; cnt[t][c0] = run; run += v; }
        dbase[t] = run;
    }
    __syncthreads();
    if (t < 64) {   // wave-parallel exclusive scan of 256 dst totals (bucket-relative)
        int i0 = t * 4;
        int a0 = dbase[i0 + 0], a1 = dbase[i0 + 1], a2 = dbase[i0 + 2], a3 = dbase[i0 + 3];
        int s1 = a0 + a1, s2 = s1 + a2, s3 = s2 + a3;
        int inc = s3;
        #pragma unroll
        for (int off = 1; off < 64; off <<= 1) {
            int nv = __shfl_up(inc, off, 64);
            if (t >= off) inc += nv;
        }
        int excl = inc - s3;                 // RELATIVE (no base)
        dbase[i0 + 0] = excl;
        dbase[i0 + 1] = excl + a0;
        dbase[i0 + 2] = excl + s1;
        dbase[i0 + 3] = excl + s2;
    }
    __syncthreads();
    {   // relative cell starts; emit row_ptr + invdeg before cursors move
        int db = dbase[t];
        int deg = ((t == CBN - 1) ? n : dbase[t + 1]) - db;
        #pragma unroll
        for (int c0 = 0; c0 < NCHUNK; ++c0) cnt[t][c0] += db;
        int node = cb * CBN + t;
        if (node < N_NODES) {
            row_ptr[node] = base + db;
            invdeg[node] = 1.0f / (float)max(deg, 1);
        }
    }
    __syncthreads();
    for (int i = t; i < n; i += 256) {       // sort into LDS (relative positions)
        u32 ev = ce[i];
        int pos = atomicAdd(&cnt[ev >> 16][CHUNK_OF(ev & 0xFFFFu)], 1);
        stage[pos] = (int)(ev & 0xFFFFu);
    }
    __syncthreads();
    for (int i = t; i < n; i += 256)         // coalesced int writes
        csr_src[base + i] = stage[i];
}

// ---------------- fused SAGE layer: fp8 gather agg tile into LDS, then MFMA ----------------
// R25 form (proven 47.3 us): 16-node tiles, 128 thr (2 waves), 4.4 KB LDS,
// 3128 blocks; int32 csr_src (dwordx4 index-load merge). Byte-identical to R25.
__global__ __launch_bounds__(128) void sage_fused_kernel(
        const unsigned short* __restrict__ h,    // [MPAD][128] bf16 (self term)
        const unsigned char*  __restrict__ h8,   // [MPAD][128] fp8  (gather)
        const int* __restrict__ row_ptr,
        const int* __restrict__ csr_src,
        const float* __restrict__ invdeg,
        const unsigned short* __restrict__ Wcat, // [128 n][256 k] bf16
        const float* __restrict__ bias,
        unsigned short* __restrict__ out,
        unsigned char*  __restrict__ out8,       // fp8 copy for next layer's gather (null l=4)
        const int* __restrict__ pool_batch,      // null for layers 1-4
        float* __restrict__ gsum) {
    __shared__ unsigned short As[16][136];
    int t = threadIdx.x;
    int node0 = blockIdx.x * 16;

    // ---- phase 1: gather (16 node-slots x 8 lanes, one pass) ----
    {
        int slot = t >> 3;       // 0..15
        int lane = t & 7;
        int c = lane * 16;       // feature offset (16 fp8 per lane)
        int node = node0 + slot;
        float acc[16];
        #pragma unroll
        for (int i = 0; i < 16; ++i) acc[i] = 0.f;
        if (node < N_NODES) {
            int beg = row_ptr[node], end = row_ptr[node + 1];
            int e = beg;
            for (; e + 4 <= end; e += 4) {
                int s0 = csr_src[e + 0];
                int s1 = csr_src[e + 1];
                int s2 = csr_src[e + 2];
                int s3 = csr_src[e + 3];
                uint4 v0 = *(const uint4*)&h8[(size_t)s0 * FDIM + c];
                uint4 v1 = *(const uint4*)&h8[(size_t)s1 * FDIM + c];
                uint4 v2 = *(const uint4*)&h8[(size_t)s2 * FDIM + c];
                uint4 v3 = *(const uint4*)&h8[(size_t)s3 * FDIM + c];
                ACC16(v0); ACC16(v1); ACC16(v2); ACC16(v3);
            }
            for (; e < end; ++e) {
                int s = csr_src[e];
                uint4 v = *(const uint4*)&h8[(size_t)s * FDIM + c];
                ACC16(v);
            }
            float inv = invdeg[node];
            #pragma unroll
            for (int i = 0; i < 16; ++i) acc[i] *= inv;
        }
        uint4 o0, o1;
        o0.x = (u32)f2bf(acc[0])  | ((u32)f2bf(acc[1])  << 16);
        o0.y = (u32)f2bf(acc[2])  | ((u32)f2bf(acc[3])  << 16);
        o0.z = (u32)f2bf(acc[4])  | ((u32)f2bf(acc[5])  << 16);
        o0.w = (u32)f2bf(acc[6])  | ((u32)f2bf(acc[7])  << 16);
        o1.x = (u32)f2bf(acc[8])  | ((u32)f2bf(acc[9])  << 16);
        o1.y = (u32)f2bf(acc[10]) | ((u32)f2bf(acc[11]) << 16);
        o1.z = (u32)f2bf(acc[12]) | ((u32)f2bf(acc[13]) << 16);
        o1.w = (u32)f2bf(acc[14]) | ((u32)f2bf(acc[15]) << 16);
        *(uint4*)&As[slot][c] = o0;
        *(uint4*)&As[slot][c + 8] = o1;
    }
    __syncthreads();

    // ---- phase 2: MFMA (2 waves; wave = col-half; 16 rows x 64 cols each) ----
    int wave = t >> 6;                   // 0..1
    int lane = t & 63;
    int l15 = lane & 15;
    int q = lane >> 4;
    int half = wave;                     // col-blocks half*4 .. half*4+3

    f32x4 acc[4];
    #pragma unroll
    for (int i = 0; i < 4; ++i) acc[i] = (f32x4){0.f, 0.f, 0.f, 0.f};

    // p=0: A = agg tile (LDS), Wl (k<128)
    {
        const unsigned short* Wb = Wcat + (size_t)(half * 64 + l15) * 256 + q * 8;
        #pragma unroll
        for (int k0 = 0; k0 < 128; k0 += 32) {
            short8 a = *(const short8*)&As[l15][q * 8 + k0];
            #pragma unroll
            for (int j = 0; j < 4; ++j) {
                short8 b = *(const short8*)(Wb + (size_t)j * 16 * 256 + k0);
                acc[j] = __builtin_amdgcn_mfma_f32_16x16x32_bf16(a, b, acc[j], 0, 0, 0);
            }
        }
    }
    // p=1: A = h (global bf16), Wr (k>=128)
    {
        const unsigned short* Ab = h + (size_t)(node0 + l15) * FDIM + q * 8;
        const unsigned short* Wb = Wcat + (size_t)(half * 64 + l15) * 256 + 128 + q * 8;
        #pragma unroll
        for (int k0 = 0; k0 < 128; k0 += 32) {
            short8 a = *(const short8*)(Ab + k0);
            #pragma unroll
            for (int j = 0; j < 4; ++j) {
                short8 b = *(const short8*)(Wb + (size_t)j * 16 * 256 + k0);
                acc[j] = __builtin_amdgcn_mfma_f32_16x16x32_bf16(a, b, acc[j], 0, 0, 0);
            }
        }
    }

    if (pool_batch == nullptr) {
        // epilogue: bias + relu + bf16 store + fp8 store (next layer's gather copy)
        #pragma unroll
        for (int j = 0; j < 4; ++j) {
            int col = (half * 4 + j) * 16 + l15;
            float bv = bias[col];
            #pragma unroll
            for (int r = 0; r < 4; ++r) {
                int row = node0 + q * 4 + r;
                float v = fmaxf(acc[j][r] + bv, 0.f);
                out[(size_t)row * FDIM + col] = f2bf(v);
                int pk = __builtin_amdgcn_cvt_pk_fp8_f32(v, v, 0, false);
                out8[(size_t)row * FDIM + col] = (unsigned char)(pk & 0xff);
            }
        }
    } else {
        // layer-5 epilogue: stage relu tile in LDS, in-block sorted-batch reduction
        __syncthreads();                 // all waves done READING As (p=0)
        #pragma unroll
        for (int j = 0; j < 4; ++j) {
            int col = (half * 4 + j) * 16 + l15;
            float bv = bias[col];
            #pragma unroll
            for (int r = 0; r < 4; ++r) {
                int rl = q * 4 + r;
                As[rl][col] = f2bf(fmaxf(acc[j][r] + bv, 0.f));
            }
        }
        __syncthreads();
        {   // t in [0,128): one thread per feature column
            int f = t;
            int nmax = min(16, N_NODES - node0);
            float a = 0.0f;
            int cur = pool_batch[node0];
            for (int r = 0; r < nmax; ++r) {
                int b = pool_batch[node0 + r];     // broadcast read
                if (b != cur) {
                    atomicAdd(&gsum[cur * FDIM + f], a);
                    a = 0.0f;
                    cur = b;
                }
                a += bflo((u32)As[r][f]);
            }
            atomicAdd(&gsum[cur * FDIM + f], a);
        }
    }
}

// ---------------- final MLP head (fp32): sigmoid(relu((gsum/cnt)@Wf1+bf1)@Wf2+bf2) -------
__global__ void mlp_kernel(const float* __restrict__ gsum,
                           const float* __restrict__ invcnt,
                           const float* __restrict__ Wf1, const float* __restrict__ bf1,
                           const float* __restrict__ Wf2, const float* __restrict__ bf2,
                           float* __restrict__ out) {
    int gg = blockIdx.x;
    int j = threadIdx.x;   // 128
    __shared__ float row[128];
    __shared__ float red[128];
    row[j] = gsum[gg * 128 + j] * invcnt[gg];
    __syncthreads();
    float acc = bf1[j];
    for (int k = 0; k < 128; ++k) acc = fmaf(row[k], Wf1[k * 128 + j], acc);
    float v = fmaxf(acc, 0.0f);
    red[j] = v * Wf2[j];
    __syncthreads();
    for (int off = 64; off > 0; off >>= 1) {
        if (j < off) red[j] += red[j + off];
        __syncthreads();
    }
    if (j == 0) out[gg] = 1.0f / (1.0f + expf(-(red[0] + bf2[0])));
}

extern "C" void kernel_launch(void* const* d_in, const int* in_sizes, int n_in,
                              void* d_out, int out_size, void* d_ws, size_t ws_size,
                              hipStream_t stream) {
    const float* x      = (const float*)d_in[0];
    const int*   edges  = (const int*)d_in[1];
    const int*   batch  = (const int*)d_in[2];
    WPtrs wp;
    const float* bs[5];
    for (int l = 0; l < 5; ++l) {
        wp.wl[l] = (const float*)d_in[3 + 3 * l];
        wp.wr[l] = (const float*)d_in[4 + 3 * l];
        bs[l]    = (const float*)d_in[5 + 3 * l];
    }
    const float* Wf1 = (const float*)d_in[18];
    const float* bf1 = (const float*)d_in[19];
    const float* Wf2 = (const float*)d_in[20];
    const float* bf2 = (const float*)d_in[21];
    float* out = (float*)d_out;

    // workspace carve-up (256B aligned)
    char* ws = (char*)d_ws;
    auto alloc = [&](size_t bytes) { void* p = (void*)ws; ws += (bytes + 255) & ~(size_t)255; return p; };
    unsigned short* xb   = (unsigned short*)alloc((size_t)MPAD * FDIM * 2);
    unsigned short* hA   = (unsigned short*)alloc((size_t)MPAD * FDIM * 2);
    unsigned short* hB   = (unsigned short*)alloc((size_t)MPAD * FDIM * 2);
    unsigned short* wcat = (unsigned short*)alloc((size_t)5 * 128 * 256 * 2);
    u32*   coarse   = (u32*)alloc((size_t)N_EDGES * 4);
    int*   g_hist   = (int*)alloc((size_t)NCB * ABLK * 4);
    int*   g_base   = (int*)alloc((size_t)NCB * ABLK * 4);
    int*   cbtotal  = (int*)alloc((size_t)NCB * 4);
    int*   row_ptr  = (int*)alloc((size_t)(N_NODES + 1) * 4);
    int*   csr_src  = (int*)alloc((size_t)N_EDGES * 4);   // R28: back to int32
    float* invdeg   = (float*)alloc((size_t)N_NODES * 4);
    float* gsum     = (float*)alloc((size_t)NGRAPH * FDIM * 4);
    float* invcnt   = (float*)alloc((size_t)NGRAPH * 4);
    unsigned char* h8A = (unsigned char*)alloc((size_t)MPAD * FDIM);  // +6.4 MB
    // lifetime-aliased fp8 buffers (no extra ws):
    //   xb8 lives in hB  : read by layer 0 only; hB first written by layer 1.
    //   h8B lives in xb  : xb dead after layer 0; h8B written by layer 1.
    unsigned char* xb8 = (unsigned char*)hB;
    unsigned char* h8B = (unsigned char*)xb;
    (void)ws_size; (void)in_sizes; (void)n_in; (void)out_size;

    // ---- conversions + CSR build (deterministic multi-split, (dst,src-chunk) order) ----
    pre_kernel<<<CVT_BLOCKS + ABLK + WCONV_BLOCKS, 256, 0, stream>>>(
        x, xb, xb8, edges, g_hist, wp, wcat, batch, gsum, invcnt);
    scan1_kernel<<<NCB, 64, 0, stream>>>(g_hist, g_base, cbtotal, row_ptr);
    scatter_kernel<<<ABLK, 256, 0, stream>>>(edges, g_base, cbtotal, coarse);
    csr_kernel<<<NCB, 256, 0, stream>>>(cbtotal, coarse, csr_src, row_ptr, invdeg);

    // ---- 5 fused SAGE layers; layer 5 folds the graph mean-pool ----
    const unsigned short* hcur  = xb;
    const unsigned char*  h8cur = xb8;
    unsigned short* bufs[2]  = {hA, hB};
    unsigned char*  bufs8[2] = {h8A, h8B};
    for (int l = 0; l < 5; ++l) {
        unsigned short* hnext  = bufs[l & 1];
        unsigned char*  h8next = (l == 4) ? nullptr : bufs8[l & 1];
        const int* pb = (l == 4) ? batch : nullptr;
        sage_fused_kernel<<<MPAD / 16, 128, 0, stream>>>(
            hcur, h8cur, row_ptr, csr_src, invdeg, wcat + ((size_t)l << 15), bs[l],
            hnext, h8next, pb, gsum);
        hcur = hnext;
        h8cur = bufs8[l & 1];
    }

    // ---- head ----
    mlp_kernel<<<NGRAPH, 128, 0, stream>>>(gsum, invcnt, Wf1, bf1, Wf2, bf2, out);
}